// Round 1
// baseline (522.787 us; speedup 1.0000x reference)
//
#include <hip/hip_runtime.h>

// Problem constants (fixed by the reference)
#define BATCH   32
#define C_OUT_N 128
#define NK      5
#define C_IN_N  (NK * C_OUT_N)   // 640
#define HIN     58
#define WIN     58
#define HOUT    56
#define WOUT    56
#define NPIX    (HOUT * WOUT)                       // 3136
#define OUT_PLANE ((size_t)BATCH * C_OUT_N * NPIX)  // 12,845,056

__global__ __launch_bounds__(256) void addshift_fused_kernel(
    const float* __restrict__ x,          // (B, C_IN, 58, 58)
    const int*   __restrict__ pad_hv,     // (C_IN, 8): [0..3]=h shifts, [4..7]=v shifts
    const int*   __restrict__ idx_id,     // (C_OUT, 4), values in [co*5, co*5+5)
    float*       __restrict__ out)        // out_h | out_v | out_id concatenated
{
    const int bc = blockIdx.x;            // b * C_OUT + co
    const int b  = bc / C_OUT_N;
    const int co = bc % C_OUT_N;

    __shared__ int s_padh[NK][4];
    __shared__ int s_padv[NK][4];
    __shared__ int s_idcnt[NK];

    if (threadIdx.x < NK * 8) {
        int k = threadIdx.x >> 3;
        int j = threadIdx.x & 7;
        int v = pad_hv[(co * NK + k) * 8 + j];
        if (j < 4) s_padh[k][j] = v;
        else       s_padv[k][j - 4] = v;
    }
    if (threadIdx.x == 0) {
        int cnt[NK] = {0, 0, 0, 0, 0};
        #pragma unroll
        for (int g = 0; g < 4; ++g) {
            int c = idx_id[co * 4 + g];
            cnt[c - co * NK]++;
        }
        #pragma unroll
        for (int k = 0; k < NK; ++k) s_idcnt[k] = cnt[k];
    }
    __syncthreads();

    const float* xbase = x + (size_t)(b * C_IN_N + co * NK) * (HIN * WIN);

    for (int p = threadIdx.x; p < NPIX; p += 256) {
        const int h = p / WOUT;
        const int w = p % WOUT;

        float sh = 0.f, sv = 0.f, sid = 0.f;
        #pragma unroll
        for (int k = 0; k < NK; ++k) {
            const float* Xc   = xbase + k * (HIN * WIN);
            const float* rowp = Xc + (h + 1) * WIN;
            #pragma unroll
            for (int g = 0; g < 4; ++g) {
                int col = w + 1 + s_padh[k][g];
                if ((unsigned)col < (unsigned)WIN) sh += rowp[col];
                int row = h + 1 + s_padv[k][g];
                if ((unsigned)row < (unsigned)HIN) sv += Xc[row * WIN + (w + 1)];
            }
            sid += (float)s_idcnt[k] * rowp[w + 1];
        }

        const size_t oidx = (size_t)bc * NPIX + p;
        out[oidx]                 = sh;
        out[OUT_PLANE + oidx]     = sv;
        out[2 * OUT_PLANE + oidx] = sid;
    }
}

extern "C" void kernel_launch(void* const* d_in, const int* in_sizes, int n_in,
                              void* d_out, int out_size, void* d_ws, size_t ws_size,
                              hipStream_t stream) {
    const float* x       = (const float*)d_in[0];
    const int*   pad_hv  = (const int*)d_in[1];
    const int*   idx_id  = (const int*)d_in[2];
    float*       out     = (float*)d_out;

    addshift_fused_kernel<<<dim3(BATCH * C_OUT_N), dim3(256), 0, stream>>>(
        x, pad_hv, idx_id, out);
}

// Round 2
// 145.600 us; speedup vs baseline: 3.5906x; 3.5906x over previous
//
#include <hip/hip_runtime.h>

// Problem constants (fixed by the reference)
#define BATCH   32
#define C_OUT_N 128
#define NK      5
#define C_IN_N  (NK * C_OUT_N)   // 640
#define HIN     58
#define WIN     58
#define HOUT    56
#define WOUT    56
#define NPIX    (HOUT * WOUT)                       // 3136
#define OUT_PLANE ((size_t)BATCH * C_OUT_N * NPIX)  // 12,845,056

// LDS tile: [NK][HIN][LDS_STRIDE], columns padded: 7 left (cols -7..-1),
// 3 right (cols 58..60). Shifts span [-8,+4] so col' = (w+1+s)+7 in [0,68).
#define LDS_STRIDE 68
#define LDS_ROWS   (NK * HIN)                // 290
#define LDS_DWORDS (LDS_ROWS * LDS_STRIDE)   // 19720  (78,880 B -> 2 blocks/CU)
#define CH_STRIDE  (HIN * LDS_STRIDE)        // 3944

__global__ __launch_bounds__(256, 2) void addshift_lds_kernel(
    const float* __restrict__ x,          // (B, C_IN, 58, 58)
    const int*   __restrict__ pad_hv,     // (C_IN, 8): [0..3]=h shifts, [4..7]=v shifts
    const int*   __restrict__ idx_id,     // (C_OUT, 4), values in [co*5, co*5+5)
    float*       __restrict__ out)        // out_h | out_v | out_id concatenated
{
    extern __shared__ float lds[];

    const int bc  = blockIdx.x;           // b * C_OUT + co
    const int b   = bc / C_OUT_N;
    const int co  = bc - b * C_OUT_N;
    const int tid = threadIdx.x;

    // ---- zero the column margins (disjoint from interior; no extra barrier)
    for (int i = tid; i < LDS_ROWS * 10; i += 256) {
        int j = i / 10;
        int m = i - j * 10;
        int c = (m < 7) ? m : (58 + m);    // m<7 -> left pad; else 65..67
        lds[j * LDS_STRIDE + c] = 0.0f;
    }

    // ---- stage the contiguous 5-channel chunk into padded LDS (read x once)
    const float* xbase = x + (size_t)(b * C_IN_N + co * NK) * (HIN * WIN);
    for (int i = tid; i < NK * HIN * WIN; i += 256) {
        int j = i / WIN;                   // global row index 0..289
        int c = i - j * WIN;               // col 0..57
        lds[j * LDS_STRIDE + 7 + c] = xbase[i];
    }

    // ---- uniform shift tables -> registers (block-uniform, compiler scalarizes)
    int   sh_s[NK][4], sv_s[NK][4];
    float cntf[NK];
    {
        int c0 = 0, c1 = 0, c2 = 0, c3 = 0, c4 = 0;
        #pragma unroll
        for (int g = 0; g < 4; ++g) {
            int c = idx_id[co * 4 + g] - co * NK;
            c0 += (c == 0); c1 += (c == 1); c2 += (c == 2); c3 += (c == 3); c4 += (c == 4);
        }
        cntf[0] = (float)c0; cntf[1] = (float)c1; cntf[2] = (float)c2;
        cntf[3] = (float)c3; cntf[4] = (float)c4;
    }
    #pragma unroll
    for (int k = 0; k < NK; ++k) {
        #pragma unroll
        for (int g = 0; g < 4; ++g) {
            sh_s[k][g] = pad_hv[(co * NK + k) * 8 + g];
            sv_s[k][g] = pad_hv[(co * NK + k) * 8 + 4 + g];
        }
    }

    __syncthreads();

    // ---- compute: all reads from LDS
    for (int p = tid; p < NPIX; p += 256) {
        int h = p / WOUT;
        int w = p - h * WOUT;
        int basew = (h + 1) * LDS_STRIDE + (w + 8);   // col' for s=0 is w+8

        float sh = 0.f, sv = 0.f, sid = 0.f;
        #pragma unroll
        for (int k = 0; k < NK; ++k) {
            const float* ch = lds + k * CH_STRIDE;
            sid += cntf[k] * ch[basew];
            #pragma unroll
            for (int g = 0; g < 4; ++g) {
                // horizontal: padding makes all columns valid, no check
                sh += ch[basew + sh_s[k][g]];
                // vertical: clamp row, zero if out of range
                int r  = h + 1 + sv_s[k][g];
                int rc = r < 0 ? 0 : (r > 57 ? 57 : r);
                float v = ch[rc * LDS_STRIDE + (w + 8)];
                sv += ((unsigned)r < 58u) ? v : 0.0f;
            }
        }

        size_t o = (size_t)bc * NPIX + p;
        out[o]                 = sh;
        out[OUT_PLANE + o]     = sv;
        out[2 * OUT_PLANE + o] = sid;
    }
}

extern "C" void kernel_launch(void* const* d_in, const int* in_sizes, int n_in,
                              void* d_out, int out_size, void* d_ws, size_t ws_size,
                              hipStream_t stream) {
    const float* x      = (const float*)d_in[0];
    const int*   pad_hv = (const int*)d_in[1];
    const int*   idx_id = (const int*)d_in[2];
    float*       out    = (float*)d_out;

    addshift_lds_kernel<<<dim3(BATCH * C_OUT_N), dim3(256), LDS_DWORDS * 4, stream>>>(
        x, pad_hv, idx_id, out);
}